// Round 8
// baseline (627.176 us; speedup 1.0000x reference)
//
#include <hip/hip_runtime.h>
#include <hip/hip_fp16.h>
#include <math.h>

// ---------------------------------------------------------------------------
// CombinedHiddenGCVAE — round 8:
//  - k_agg8 v3: 4B/lane owner-lane gathers (32 lanes per 128B row -> 2 edges
//    per wave-instruction), 8-deep unroll = 16 edges / 2KB in flight per wave
//    (2x round 7). float4 accumulator, single shfl_xor(32) reduce for W=128.
//  - Rest identical to round 7 (LDS index staging, fp8 tables, atomic-free
//    CSR build, MFMA f16 GEMMs with fused epilogues).
// ---------------------------------------------------------------------------

#define FEAT 128
#define COND 32
#define HID  128
#define LAT  64

#define NG    8       // dst-range groups (== XCDs)
#define RANGE 12500   // nodes per group (N=100000)
#define BPG   32      // blocks per group

typedef _Float16 f16x8 __attribute__((ext_vector_type(8)));
typedef float f32x4 __attribute__((ext_vector_type(4)));
typedef float floatx2 __attribute__((ext_vector_type(2)));
typedef float floatx4 __attribute__((ext_vector_type(4)));

__device__ __forceinline__ uint pk2(float x, float y) {
  __half2 h = __floats2half2_rn(x, y);
  return __builtin_bit_cast(uint, h);
}
__device__ __forceinline__ floatx2 up8lo(uint u) {
  return __builtin_amdgcn_cvt_pk_f32_fp8(u, false);
}
__device__ __forceinline__ floatx2 up8hi(uint u) {
  return __builtin_amdgcn_cvt_pk_f32_fp8(u, true);
}
__device__ __forceinline__ uint pk8(float a, float b) {
  return (uint)__builtin_amdgcn_cvt_pk_fp8_f32(a, b, 0, false);
}
__device__ __forceinline__ unsigned char pk8b(float a) {
  return (unsigned char)(pk8(a, a) & 0xff);
}

// ---------------- prep: LDS histogram -> partial counts ----------------
__global__ __launch_bounds__(256) void k_hist(const int* __restrict__ dstArr,
                                              int* __restrict__ part, int E, int n) {
  __shared__ int bins[RANGE];
  const int g = blockIdx.x & (NG - 1), bi = blockIdx.x >> 3;
  const int lo = g * RANGE;
  const int hi = min(n, lo + RANGE);
  for (int ii = threadIdx.x; ii < RANGE; ii += 256) bins[ii] = 0;
  __syncthreads();
  const int quads = E >> 2;
  const int per = (quads + BPG - 1) / BPG;
  const int q0 = bi * per, q1 = min(quads, q0 + per);
  const int4* d4 = (const int4*)dstArr;
  for (int q = q0 + threadIdx.x; q < q1; q += 256) {
    int4 d = d4[q];
    if (d.x >= lo && d.x < hi) atomicAdd(&bins[d.x - lo], 1);
    if (d.y >= lo && d.y < hi) atomicAdd(&bins[d.y - lo], 1);
    if (d.z >= lo && d.z < hi) atomicAdd(&bins[d.z - lo], 1);
    if (d.w >= lo && d.w < hi) atomicAdd(&bins[d.w - lo], 1);
  }
  if (bi == 0) {
    for (int e = (quads << 2) + threadIdx.x; e < E; e += 256) {
      int d = dstArr[e];
      if (d >= lo && d < hi) atomicAdd(&bins[d - lo], 1);
    }
  }
  __syncthreads();
  int* dst = part + (size_t)(g * BPG + bi) * RANGE;
  for (int ii = threadIdx.x; ii < RANGE; ii += 256) dst[ii] = bins[ii];
}

// scan step 1: deg = sum of partials; dis = rsqrt(deg+1); ptr prefix of deg
__global__ void k_scan1(const int* __restrict__ part, int* __restrict__ degI,
                        float* __restrict__ dis, int* __restrict__ ptr,
                        int* __restrict__ blkSum, int n) {
  __shared__ int wtot[4];
  int tid = threadIdx.x, lane = tid & 63, wid = tid >> 6;
  int base = blockIdx.x * 1024 + tid * 4;
  int v[4];
#pragma unroll
  for (int j = 0; j < 4; j++) {
    int i = base + j;
    int c = 0;
    if (i < n) {
      int g = i / RANGE, ii = i - g * RANGE;
      const int* p = part + (size_t)g * BPG * RANGE + ii;
      for (int b = 0; b < BPG; b++) c += p[(size_t)b * RANGE];
      degI[i] = c;
      dis[i] = rsqrtf((float)(c + 1));
    }
    v[j] = c;
  }
  int tsum = v[0] + v[1] + v[2] + v[3];
  int x = tsum;
#pragma unroll
  for (int off = 1; off < 64; off <<= 1) {
    int y = __shfl_up(x, off);
    if (lane >= off) x += y;
  }
  if (lane == 63) wtot[wid] = x;
  __syncthreads();
  int wbase = 0;
  for (int w = 0; w < wid; w++) wbase += wtot[w];
  int run = wbase + (x - tsum);
#pragma unroll
  for (int j = 0; j < 4; j++) {
    int i = base + j;
    if (i < n) ptr[i] = run;
    run += v[j];
  }
  if (tid == blockDim.x - 1) blkSum[blockIdx.x] = wbase + x;
}

__global__ void k_scan2(const int* __restrict__ blkSum, int* __restrict__ blkOff, int nb) {
  __shared__ int wtot[4];
  int tid = threadIdx.x, lane = tid & 63, wid = tid >> 6;
  int v = (tid < nb) ? blkSum[tid] : 0;
  int x = v;
#pragma unroll
  for (int off = 1; off < 64; off <<= 1) {
    int y = __shfl_up(x, off);
    if (lane >= off) x += y;
  }
  if (lane == 63) wtot[wid] = x;
  __syncthreads();
  int wbase = 0;
  for (int w = 0; w < wid; w++) wbase += wtot[w];
  if (tid < nb) blkOff[tid] = wbase + x - v;
}

__global__ void k_scan3(int* __restrict__ ptr, const int* __restrict__ blkOff, int n) {
  int i = blockIdx.x * blockDim.x + threadIdx.x;
  if (i < n) ptr[i] += blkOff[i >> 10];
}

// column prefix over per-block partials + ptr -> per-block base cursors
__global__ void k_cum(int* __restrict__ part, const int* __restrict__ ptr, int n) {
  int i = blockIdx.x * blockDim.x + threadIdx.x;
  if (i >= n) return;
  int g = i / RANGE, ii = i - g * RANGE;
  int* p = part + (size_t)g * BPG * RANGE + ii;
  int run = ptr[i];
  for (int b = 0; b < BPG; b++) {
    int t = p[(size_t)b * RANGE];
    p[(size_t)b * RANGE] = run;
    run += t;
  }
}

// LDS-cursor CSR fill; identical slicing to k_hist
__global__ __launch_bounds__(256) void k_fill2(const int* __restrict__ ei,
                                               const int* __restrict__ part,
                                               int* __restrict__ csr, int E, int n) {
  __shared__ int cur[RANGE];
  const int g = blockIdx.x & (NG - 1), bi = blockIdx.x >> 3;
  const int lo = g * RANGE;
  const int hi = min(n, lo + RANGE);
  const int* base = part + (size_t)(g * BPG + bi) * RANGE;
  for (int ii = threadIdx.x; ii < RANGE; ii += 256) cur[ii] = base[ii];
  __syncthreads();
  const int quads = E >> 2;
  const int per = (quads + BPG - 1) / BPG;
  const int q0 = bi * per, q1 = min(quads, q0 + per);
  const int4* s4 = (const int4*)ei;
  const int4* d4 = (const int4*)(ei + E);
  for (int q = q0 + threadIdx.x; q < q1; q += 256) {
    int4 s = s4[q], d = d4[q];
    if (d.x >= lo && d.x < hi) csr[atomicAdd(&cur[d.x - lo], 1)] = s.x;
    if (d.y >= lo && d.y < hi) csr[atomicAdd(&cur[d.y - lo], 1)] = s.y;
    if (d.z >= lo && d.z < hi) csr[atomicAdd(&cur[d.z - lo], 1)] = s.z;
    if (d.w >= lo && d.w < hi) csr[atomicAdd(&cur[d.w - lo], 1)] = s.w;
  }
  if (bi == 0) {
    for (int e = (quads << 2) + threadIdx.x; e < E; e += 256) {
      int d = ei[E + e];
      if (d >= lo && d < hi) csr[atomicAdd(&cur[d - lo], 1)] = ei[e];
    }
  }
}

// ---------------- fp32 [N,32] -> fp8 with dis prescale (cond) -------------
__global__ void k_cast8(const float* __restrict__ src, uint* __restrict__ dst,
                        const float* __restrict__ dis, int n4) {
  int t = blockIdx.x * blockDim.x + threadIdx.x;
  if (t >= n4) return;
  size_t i4 = (size_t)t * 4;
  int row = (int)(i4 >> 5);
  float d = dis[row];
  float4 v = *(const float4*)&src[i4];
  uint r = (uint)__builtin_amdgcn_cvt_pk_fp8_f32(d * v.x, d * v.y, 0, false);
  r = (uint)__builtin_amdgcn_cvt_pk_fp8_f32(d * v.z, d * v.w, (int)r, true);
  dst[t] = r;
}

// ---------------- weight pack: fp32 [K,N] -> f16 fragment layout ----------
struct PW { const float* src; unsigned short* dst; int K, Ncols, colOff, NnTot; };
struct PWArr { PW d[7]; };

__global__ void k_packw(PWArr a) {
  PW d = a.d[blockIdx.y];
  int t = blockIdx.x * blockDim.x + threadIdx.x;
  if (t >= d.K * d.Ncols) return;
  int k = t / d.Ncols;
  int n = t - k * d.Ncols;
  float v = d.src[t];
  d.dst[((size_t)(k >> 3) * d.NnTot + d.colOff + n) * 8 + (k & 7)] =
      __builtin_bit_cast(unsigned short, (_Float16)v);
}

// ---------------- fp8 owner-lane aggregation, v3 --------------------------
// 4B/lane: LPR = W/4 lanes per row, NB = 64/LPR edges per wave-instruction,
// 8-deep unroll = 8*NB edges in flight. LDS index staging as in v2.
// OUTK 0: Yv = f16 stream [n][W]   OUTK 1: Yv = fp8 table, tanh epilogue
template <int W, int OUTK>
__global__ __launch_bounds__(256) void k_agg8(
    const unsigned char* __restrict__ X8, void* __restrict__ Yv,
    const int* __restrict__ degI, const float* __restrict__ dis,
    const int* __restrict__ ptr, const int* __restrict__ csr,
    const float* __restrict__ bias, int n) {
  constexpr int LPR = W / 4;    // lanes per row (4B each)
  constexpr int NB = 64 / LPR;  // edges per issue: 128->2, 64->4, 32->8
  __shared__ int idxs[4][72];   // per-wave private index stage
  const int wvw = threadIdx.x >> 6;
  const int l = threadIdx.x & 63;
  const int sub = l / LPR;            // edge slot within an issue
  const int boff = (l % LPR) * 4;     // byte offset within row
  const unsigned char* __restrict__ Xb = X8 + boff;
  const int stride = gridDim.x * 4;

  for (int i = blockIdx.x * 4 + wvw; i < n; i += stride) {
    const int p0 = ptr[i];
    const int cnt = degI[i];
    if (l < cnt) idxs[wvw][l] = csr[p0 + l];
    floatx4 acc;
    {
      uint u = *(const uint*)(Xb + (size_t)i * W);
      floatx2 lo = up8lo(u), hi = up8hi(u);
      bool own = (sub == 0);
      acc.x = own ? lo.x : 0.f;
      acc.y = own ? lo.y : 0.f;
      acc.z = own ? hi.x : 0.f;
      acc.w = own ? hi.y : 0.f;
    }
    const int m = min(cnt, 64);
    int e = 0;
    // 8 wave-instructions (8*NB edges) in flight
    for (; e + 8 * NB <= m; e += 8 * NB) {
      uint u[8];
#pragma unroll
      for (int j = 0; j < 8; j++) {
        int s = idxs[wvw][e + j * NB + sub];
        u[j] = *(const uint*)(Xb + ((size_t)(uint)s * W));
      }
#pragma unroll
      for (int j = 0; j < 8; j++) {
        floatx2 lo = up8lo(u[j]), hi = up8hi(u[j]);
        acc.x += lo.x; acc.y += lo.y; acc.z += hi.x; acc.w += hi.y;
      }
    }
    for (; e < m; e += NB) {
      int ii = e + sub;
      if (ii < m) {
        uint u = *(const uint*)(Xb + ((size_t)(uint)idxs[wvw][ii] * W));
        floatx2 lo = up8lo(u), hi = up8hi(u);
        acc.x += lo.x; acc.y += lo.y; acc.z += hi.x; acc.w += hi.y;
      }
    }
    for (; e < cnt; e += NB) {  // rare: degree > 64
      int ii = e + sub;
      if (ii < cnt) {
        uint u = *(const uint*)(Xb + ((size_t)(uint)csr[p0 + ii] * W));
        floatx2 lo = up8lo(u), hi = up8hi(u);
        acc.x += lo.x; acc.y += lo.y; acc.z += hi.x; acc.w += hi.y;
      }
    }
#pragma unroll
    for (int mask = LPR; mask < 64; mask <<= 1) {
      acc.x += __shfl_xor(acc.x, mask);
      acc.y += __shfl_xor(acc.y, mask);
      acc.z += __shfl_xor(acc.z, mask);
      acc.w += __shfl_xor(acc.w, mask);
    }
    if (sub == 0) {
      float di = dis[i];
      float a0 = di * acc.x, a1 = di * acc.y, a2 = di * acc.z, a3 = di * acc.w;
      if (OUTK == 1) {
        float4 b = *(const float4*)&bias[boff];
        uint p = (uint)__builtin_amdgcn_cvt_pk_fp8_f32(
            di * tanhf(a0 + b.x), di * tanhf(a1 + b.y), 0, false);
        p = (uint)__builtin_amdgcn_cvt_pk_fp8_f32(
            di * tanhf(a2 + b.z), di * tanhf(a3 + b.w), (int)p, true);
        *(uint*)((unsigned char*)Yv + (size_t)i * W + boff) = p;
      } else {
        uint2 o;
        o.x = pk2(a0, a1);
        o.y = pk2(a2, a3);
        *(uint2*)((unsigned char*)Yv + ((size_t)i * W + boff) * 2) = o;
      }
    }
  }
}

// ---------------- MFMA f16 GEMM, NN=128, BM=128 (4 waves x 32 rows) -------
// MODE 0: O8 = fp8(dis*tanh(v+b1))   MODE 1: mean/lv/z fused   MODE 2: O1 = v+b1
template <int KT, int MODE>
__global__ __launch_bounds__(256) void k_gemm16(
    const _Float16* __restrict__ A1, int K1,
    const _Float16* __restrict__ A2, int K2,
    const unsigned short* __restrict__ Wp,
    const float* __restrict__ b1, const float* __restrict__ b2,
    float* __restrict__ O1, float* __restrict__ O2, float* __restrict__ O3,
    unsigned char* __restrict__ O8,
    const float* __restrict__ noise, const float* __restrict__ dis, int M) {
  __shared__ unsigned short wl[(KT / 8) * 1024];
  const int tid = threadIdx.x;
  const int l = tid & 63, wid = tid >> 6;
  const int row0 = blockIdx.x * 128;
  constexpr int totalU16 = (KT / 8) * 1024;
  for (int o = tid * 8; o < totalU16; o += 256 * 8) {
    *(uint4*)&wl[o] = *(const uint4*)&Wp[o];
  }
  __syncthreads();

  const int ar = l & 15, kg = l >> 4;
  f32x4 acc[2][8] = {};
  for (int k0 = 0; k0 < KT; k0 += 32) {
    const _Float16* Ab;
    int kl, Kb;
    if (k0 < K1) { Ab = A1; kl = k0; Kb = K1; }
    else         { Ab = A2; kl = k0 - K1; Kb = K2; }
    f16x8 a[2];
#pragma unroll
    for (int mt = 0; mt < 2; mt++) {
      int row = row0 + wid * 32 + mt * 16 + ar;
      if (row < M) {
        a[mt] = *(const f16x8*)&Ab[(size_t)row * Kb + kl + kg * 8];
      } else {
#pragma unroll
        for (int j = 0; j < 8; j++) a[mt][j] = (_Float16)0;
      }
    }
    int lb = ((k0 >> 3) + kg) * 1024 + ar * 8;
#pragma unroll
    for (int nt = 0; nt < 8; nt++) {
      f16x8 b = *(const f16x8*)&wl[lb + nt * 128];
#pragma unroll
      for (int mt = 0; mt < 2; mt++)
        acc[mt][nt] = __builtin_amdgcn_mfma_f32_16x16x32_f16(a[mt], b, acc[mt][nt], 0, 0, 0);
    }
  }

#pragma unroll
  for (int mt = 0; mt < 2; mt++) {
    int rbase = row0 + wid * 32 + mt * 16 + (l >> 4) * 4;
#pragma unroll
    for (int r = 0; r < 4; r++) {
      int rw = rbase + r;
      if (rw >= M) continue;
      if (MODE == 1) {
        float dr = dis[rw];
#pragma unroll
        for (int nt = 0; nt < 4; nt++) {
          int c = nt * 16 + (l & 15);
          float mv = acc[mt][nt][r] + b1[c];
          float lv = acc[mt][nt + 4][r] + b2[c];
          O1[(size_t)rw * 64 + c] = mv;
          O2[(size_t)rw * 64 + c] = lv;
          float z = noise[(size_t)rw * 64 + c] * expf(0.5f * lv) + mv;
          O3[(size_t)rw * 64 + c] = z;
          O8[(size_t)rw * 64 + c] = pk8b(dr * z);
        }
      } else if (MODE == 0) {
        float dr = dis[rw];
#pragma unroll
        for (int nt = 0; nt < 8; nt++) {
          int c = nt * 16 + (l & 15);
          float v = tanhf(acc[mt][nt][r] + b1[c]);
          O8[(size_t)rw * 128 + c] = pk8b(dr * v);
        }
      } else {
#pragma unroll
        for (int nt = 0; nt < 8; nt++) {
          int c = nt * 16 + (l & 15);
          O1[(size_t)rw * 128 + c] = acc[mt][nt][r] + b1[c];
        }
      }
    }
  }
}

// ---------------- P1 GEMM: fp32 [feat|cond] inputs, prescaled fp8 out -----
__global__ __launch_bounds__(256) void k_gemmP1(
    const float* __restrict__ F, const float* __restrict__ Cnd,
    const unsigned short* __restrict__ Wp, unsigned char* __restrict__ O8,
    const float* __restrict__ dis, int M) {
  __shared__ unsigned short wl[20 * 1024];  // K=160
  const int tid = threadIdx.x;
  const int l = tid & 63, wid = tid >> 6;
  const int row0 = blockIdx.x * 128;
  for (int o = tid * 8; o < 20 * 1024; o += 256 * 8) {
    *(uint4*)&wl[o] = *(const uint4*)&Wp[o];
  }
  __syncthreads();

  const int ar = l & 15, kg = l >> 4;
  f32x4 acc[2][8] = {};
  for (int k0 = 0; k0 < 160; k0 += 32) {
    int col0 = k0 + kg * 8;
    f16x8 a[2];
#pragma unroll
    for (int mt = 0; mt < 2; mt++) {
      int row = row0 + wid * 32 + mt * 16 + ar;
      float4 u = {0, 0, 0, 0}, v = {0, 0, 0, 0};
      if (row < M) {
        if (col0 < 128) {
          u = *(const float4*)&F[(size_t)row * 128 + col0];
          v = *(const float4*)&F[(size_t)row * 128 + col0 + 4];
        } else {
          u = *(const float4*)&Cnd[(size_t)row * 32 + (col0 - 128)];
          v = *(const float4*)&Cnd[(size_t)row * 32 + (col0 - 124)];
        }
      }
      a[mt][0] = (_Float16)u.x; a[mt][1] = (_Float16)u.y;
      a[mt][2] = (_Float16)u.z; a[mt][3] = (_Float16)u.w;
      a[mt][4] = (_Float16)v.x; a[mt][5] = (_Float16)v.y;
      a[mt][6] = (_Float16)v.z; a[mt][7] = (_Float16)v.w;
    }
    int lb = ((k0 >> 3) + kg) * 1024 + ar * 8;
#pragma unroll
    for (int nt = 0; nt < 8; nt++) {
      f16x8 b = *(const f16x8*)&wl[lb + nt * 128];
#pragma unroll
      for (int mt = 0; mt < 2; mt++)
        acc[mt][nt] = __builtin_amdgcn_mfma_f32_16x16x32_f16(a[mt], b, acc[mt][nt], 0, 0, 0);
    }
  }
#pragma unroll
  for (int mt = 0; mt < 2; mt++) {
    int rbase = row0 + wid * 32 + mt * 16 + (l >> 4) * 4;
#pragma unroll
    for (int r = 0; r < 4; r++) {
      int rw = rbase + r;
      if (rw >= M) continue;
      float dr = dis[rw];
#pragma unroll
      for (int nt = 0; nt < 8; nt++) {
        int c = nt * 16 + (l & 15);
        O8[(size_t)rw * 128 + c] = pk8b(dr * acc[mt][nt][r]);
      }
    }
  }
}

// ---------------------------------------------------------------------------

static inline size_t align_up(size_t x, size_t a) { return (x + a - 1) & ~(a - 1); }

extern "C" void kernel_launch(void* const* d_in, const int* in_sizes, int n_in,
                              void* d_out, int out_size, void* d_ws, size_t ws_size,
                              hipStream_t stream) {
  const float* feature   = (const float*)d_in[0];
  const float* condition = (const float*)d_in[1];
  const float* noise     = (const float*)d_in[2];
  const int*   ei        = (const int*)d_in[3];
  const float* Wenc1 = (const float*)d_in[4];  const float* benc1 = (const float*)d_in[5];
  const float* Wenc2 = (const float*)d_in[6];  const float* benc2 = (const float*)d_in[7];
  const float* Wm    = (const float*)d_in[8];  const float* bm    = (const float*)d_in[9];
  const float* Wlv   = (const float*)d_in[10]; const float* blv   = (const float*)d_in[11];
  const float* Wd1   = (const float*)d_in[12]; const float* bd1   = (const float*)d_in[13];
  const float* Wd2   = (const float*)d_in[14]; const float* bd2   = (const float*)d_in[15];
  const float* Wout  = (const float*)d_in[16]; const float* bout  = (const float*)d_in[17];

  const int N = in_sizes[0] / FEAT;
  const int E = in_sizes[3] / 2;

  // ---- d_out segments ----
  float* out = (float*)d_out;
  float* zseg    = out;
  float* meanseg = out + (size_t)N * LAT;
  float* lvseg   = out + (size_t)2 * N * LAT;
  float* outseg  = out + (size_t)3 * N * LAT;  // fp32 [N,128]; untouched until final GEMM

  // ---- workspace ----
  char* w = (char*)d_ws;
  size_t off = 0;
  int*   degI   = (int*)(w + off);   off = align_up(off + (size_t)N * 4, 256);
  float* dis    = (float*)(w + off); off = align_up(off + (size_t)N * 4, 256);
  int*   ptr    = (int*)(w + off);   off = align_up(off + (size_t)N * 4, 256);
  int*   blkSum = (int*)(w + off);   off = align_up(off + 4096, 256);
  int*   blkOff = (int*)(w + off);   off = align_up(off + 4096, 256);
  int*   csr    = (int*)(w + off);   off = align_up(off + (size_t)(E + 64) * 4, 256);
  unsigned short* WpE1 = (unsigned short*)(w + off); off = align_up(off + 160 * 128 * 2, 256);
  unsigned short* WpE2 = (unsigned short*)(w + off); off = align_up(off + 128 * 128 * 2, 256);
  unsigned short* WpML = (unsigned short*)(w + off); off = align_up(off + 128 * 128 * 2, 256);
  unsigned short* WpD1 = (unsigned short*)(w + off); off = align_up(off + 96 * 128 * 2, 256);
  unsigned short* WpD2 = (unsigned short*)(w + off); off = align_up(off + 128 * 128 * 2, 256);
  unsigned short* WpO  = (unsigned short*)(w + off); off = align_up(off + 128 * 128 * 2, 256);
  _Float16* S  = (_Float16*)(w + off); off = align_up(off + (size_t)N * 32 * 2, 256);
  _Float16* TA = (_Float16*)(w + off); off = align_up(off + (size_t)N * 128 * 2, 256);
  unsigned char* F8A = (unsigned char*)(w + off); off = align_up(off + (size_t)N * 128, 256);
  unsigned char* F8B = (unsigned char*)(w + off); off = align_up(off + (size_t)N * 128, 256);
  unsigned char* C8  = (unsigned char*)(w + off); off = align_up(off + (size_t)N * 32, 256);
  // partial-count slab aliases TA (dead until first f16 stream write)
  int* part = (int*)TA;  // [NG*BPG][RANGE] = 12.8 MB < 25.6 MB

  const int TB_ = 256;
  dim3 blk(TB_);
  dim3 gN((N + TB_ - 1) / TB_);
  const int nScanBlk = (N + 1023) / 1024;
  dim3 gAgg(2048);   // persistent grid-stride waves: 32 waves/CU
  dim3 gG((N + 127) / 128);
  dim3 gPart(NG * BPG);

  // ---- graph prep (no global atomics) ----
  k_hist<<<gPart, blk, 0, stream>>>(ei + E, part, E, N);
  k_scan1<<<dim3(nScanBlk), blk, 0, stream>>>(part, degI, dis, ptr, blkSum, N);
  k_scan2<<<dim3(1), blk, 0, stream>>>(blkSum, blkOff, nScanBlk);
  k_scan3<<<gN, blk, 0, stream>>>(ptr, blkOff, N);
  k_cum<<<gN, blk, 0, stream>>>(part, ptr, N);
  k_fill2<<<gPart, blk, 0, stream>>>(ei, part, csr, E, N);

  // ---- cond cast (fp8) + weight packing ----
  k_cast8<<<dim3(((size_t)N * 32 / 4 + TB_ - 1) / TB_), blk, 0, stream>>>(
      condition, (uint*)C8, dis, N * 32 / 4);
  {
    PWArr pa;
    pa.d[0] = {Wenc1, WpE1, 160, 128, 0, 128};
    pa.d[1] = {Wenc2, WpE2, 128, 128, 0, 128};
    pa.d[2] = {Wm,    WpML, 128, 64,  0, 128};
    pa.d[3] = {Wlv,   WpML, 128, 64, 64, 128};
    pa.d[4] = {Wd1,   WpD1,  96, 128, 0, 128};
    pa.d[5] = {Wd2,   WpD2, 128, 128, 0, 128};
    pa.d[6] = {Wout,  WpO,  128, 128, 0, 128};
    k_packw<<<dim3(80, 7), blk, 0, stream>>>(pa);
  }

  // ---- encoder ----
  // P1 = [feat|cond]@Wenc1, prescaled fp8 -> F8A
  k_gemmP1<<<gG, blk, 0, stream>>>(feature, condition, WpE1, F8A, dis, N);
  // h1' = fp8( dis*tanh(agg(P1)+b1) ) -> F8B
  k_agg8<HID, 1><<<gAgg, blk, 0, stream>>>(F8A, F8B, degI, dis, ptr, csr, benc1, N);
  // agg(h1') -> TA (f16 stream)
  k_agg8<HID, 0><<<gAgg, blk, 0, stream>>>(F8B, TA, degI, dis, ptr, csr, nullptr, N);
  // h2' = fp8( dis*tanh(TA@We2+b2) ) -> F8A
  k_gemm16<128, 0><<<gG, blk, 0, stream>>>(
      TA, HID, nullptr, 0, WpE2, benc2, nullptr,
      nullptr, nullptr, nullptr, F8A, nullptr, dis, N);
  // agg(h2') -> TA
  k_agg8<HID, 0><<<gAgg, blk, 0, stream>>>(F8A, TA, degI, dis, ptr, csr, nullptr, N);
  // mean/lv/z (fp32 outputs) + z' fp8 -> F8B
  k_gemm16<128, 1><<<gG, blk, 0, stream>>>(
      TA, HID, nullptr, 0, WpML, bm, blv,
      meanseg, lvseg, zseg, F8B, noise, dis, N);

  // ---- decoder ----
  // agg(z') -> TA[N,64] f16 ; agg(cond') -> S[N,32] f16
  k_agg8<LAT, 0><<<gAgg, blk, 0, stream>>>(F8B, TA, degI, dis, ptr, csr, nullptr, N);
  k_agg8<COND, 0><<<gAgg, blk, 0, stream>>>(C8, S, degI, dis, ptr, csr, nullptr, N);
  // g1' = fp8( dis*tanh([aggZ|aggC]@Wd1+b) ) -> F8A
  k_gemm16<96, 0><<<gG, blk, 0, stream>>>(
      TA, LAT, S, COND, WpD1, bd1, nullptr,
      nullptr, nullptr, nullptr, F8A, nullptr, dis, N);
  // agg(g1') -> TA
  k_agg8<HID, 0><<<gAgg, blk, 0, stream>>>(F8A, TA, degI, dis, ptr, csr, nullptr, N);
  // g2' -> F8B
  k_gemm16<128, 0><<<gG, blk, 0, stream>>>(
      TA, HID, nullptr, 0, WpD2, bd2, nullptr,
      nullptr, nullptr, nullptr, F8B, nullptr, dis, N);
  // agg(g2') -> TA
  k_agg8<HID, 0><<<gAgg, blk, 0, stream>>>(F8B, TA, degI, dis, ptr, csr, nullptr, N);
  // out = TA@Wout + b -> outseg (fp32)
  k_gemm16<128, 2><<<gG, blk, 0, stream>>>(
      TA, HID, nullptr, 0, WpO, bout, nullptr,
      outseg, nullptr, nullptr, nullptr, nullptr, dis, N);
}

// Round 9
// 548.886 us; speedup vs baseline: 1.1426x; 1.1426x over previous
//
#include <hip/hip_runtime.h>
#include <hip/hip_fp16.h>
#include <math.h>

// ---------------------------------------------------------------------------
// CombinedHiddenGCVAE — round 9:
//  - k_agg8 reverted to round-7 form (2B/lane owner-lane, LDS index staging,
//    8 gathers in flight): round 8's 4B/lane was null-to-negative.
//  - Decoder layer 1 is now mult-first like the encoder: P1d = [z|cond]@Wd1
//    (GEMM on raw fp32, prescaled fp8 out) then one 128-wide agg with
//    bias+tanh epilogue. Replaces the 64-wide + 32-wide aggs + K=96 GEMM +
//    cond cast. Six symmetric 128-wide agg passes total.
// ---------------------------------------------------------------------------

#define FEAT 128
#define COND 32
#define HID  128
#define LAT  64

#define NG    8       // dst-range groups (== XCDs)
#define RANGE 12500   // nodes per group (N=100000)
#define BPG   32      // blocks per group

typedef _Float16 f16x8 __attribute__((ext_vector_type(8)));
typedef float f32x4 __attribute__((ext_vector_type(4)));
typedef float floatx2 __attribute__((ext_vector_type(2)));

__device__ __forceinline__ uint pk2(float x, float y) {
  __half2 h = __floats2half2_rn(x, y);
  return __builtin_bit_cast(uint, h);
}
__device__ __forceinline__ floatx2 up8(uint u) {
  return __builtin_amdgcn_cvt_pk_f32_fp8(u, false);
}
__device__ __forceinline__ uint pk8(float a, float b) {
  return (uint)__builtin_amdgcn_cvt_pk_fp8_f32(a, b, 0, false);
}
__device__ __forceinline__ unsigned char pk8b(float a) {
  return (unsigned char)(pk8(a, a) & 0xff);
}

// ---------------- prep: LDS histogram -> partial counts ----------------
__global__ __launch_bounds__(256) void k_hist(const int* __restrict__ dstArr,
                                              int* __restrict__ part, int E, int n) {
  __shared__ int bins[RANGE];
  const int g = blockIdx.x & (NG - 1), bi = blockIdx.x >> 3;
  const int lo = g * RANGE;
  const int hi = min(n, lo + RANGE);
  for (int ii = threadIdx.x; ii < RANGE; ii += 256) bins[ii] = 0;
  __syncthreads();
  const int quads = E >> 2;
  const int per = (quads + BPG - 1) / BPG;
  const int q0 = bi * per, q1 = min(quads, q0 + per);
  const int4* d4 = (const int4*)dstArr;
  for (int q = q0 + threadIdx.x; q < q1; q += 256) {
    int4 d = d4[q];
    if (d.x >= lo && d.x < hi) atomicAdd(&bins[d.x - lo], 1);
    if (d.y >= lo && d.y < hi) atomicAdd(&bins[d.y - lo], 1);
    if (d.z >= lo && d.z < hi) atomicAdd(&bins[d.z - lo], 1);
    if (d.w >= lo && d.w < hi) atomicAdd(&bins[d.w - lo], 1);
  }
  if (bi == 0) {
    for (int e = (quads << 2) + threadIdx.x; e < E; e += 256) {
      int d = dstArr[e];
      if (d >= lo && d < hi) atomicAdd(&bins[d - lo], 1);
    }
  }
  __syncthreads();
  int* dst = part + (size_t)(g * BPG + bi) * RANGE;
  for (int ii = threadIdx.x; ii < RANGE; ii += 256) dst[ii] = bins[ii];
}

// scan step 1: deg = sum of partials; dis = rsqrt(deg+1); ptr prefix of deg
__global__ void k_scan1(const int* __restrict__ part, int* __restrict__ degI,
                        float* __restrict__ dis, int* __restrict__ ptr,
                        int* __restrict__ blkSum, int n) {
  __shared__ int wtot[4];
  int tid = threadIdx.x, lane = tid & 63, wid = tid >> 6;
  int base = blockIdx.x * 1024 + tid * 4;
  int v[4];
#pragma unroll
  for (int j = 0; j < 4; j++) {
    int i = base + j;
    int c = 0;
    if (i < n) {
      int g = i / RANGE, ii = i - g * RANGE;
      const int* p = part + (size_t)g * BPG * RANGE + ii;
      for (int b = 0; b < BPG; b++) c += p[(size_t)b * RANGE];
      degI[i] = c;
      dis[i] = rsqrtf((float)(c + 1));
    }
    v[j] = c;
  }
  int tsum = v[0] + v[1] + v[2] + v[3];
  int x = tsum;
#pragma unroll
  for (int off = 1; off < 64; off <<= 1) {
    int y = __shfl_up(x, off);
    if (lane >= off) x += y;
  }
  if (lane == 63) wtot[wid] = x;
  __syncthreads();
  int wbase = 0;
  for (int w = 0; w < wid; w++) wbase += wtot[w];
  int run = wbase + (x - tsum);
#pragma unroll
  for (int j = 0; j < 4; j++) {
    int i = base + j;
    if (i < n) ptr[i] = run;
    run += v[j];
  }
  if (tid == blockDim.x - 1) blkSum[blockIdx.x] = wbase + x;
}

__global__ void k_scan2(const int* __restrict__ blkSum, int* __restrict__ blkOff, int nb) {
  __shared__ int wtot[4];
  int tid = threadIdx.x, lane = tid & 63, wid = tid >> 6;
  int v = (tid < nb) ? blkSum[tid] : 0;
  int x = v;
#pragma unroll
  for (int off = 1; off < 64; off <<= 1) {
    int y = __shfl_up(x, off);
    if (lane >= off) x += y;
  }
  if (lane == 63) wtot[wid] = x;
  __syncthreads();
  int wbase = 0;
  for (int w = 0; w < wid; w++) wbase += wtot[w];
  if (tid < nb) blkOff[tid] = wbase + x - v;
}

__global__ void k_scan3(int* __restrict__ ptr, const int* __restrict__ blkOff, int n) {
  int i = blockIdx.x * blockDim.x + threadIdx.x;
  if (i < n) ptr[i] += blkOff[i >> 10];
}

// column prefix over per-block partials + ptr -> per-block base cursors
__global__ void k_cum(int* __restrict__ part, const int* __restrict__ ptr, int n) {
  int i = blockIdx.x * blockDim.x + threadIdx.x;
  if (i >= n) return;
  int g = i / RANGE, ii = i - g * RANGE;
  int* p = part + (size_t)g * BPG * RANGE + ii;
  int run = ptr[i];
  for (int b = 0; b < BPG; b++) {
    int t = p[(size_t)b * RANGE];
    p[(size_t)b * RANGE] = run;
    run += t;
  }
}

// LDS-cursor CSR fill; identical slicing to k_hist
__global__ __launch_bounds__(256) void k_fill2(const int* __restrict__ ei,
                                               const int* __restrict__ part,
                                               int* __restrict__ csr, int E, int n) {
  __shared__ int cur[RANGE];
  const int g = blockIdx.x & (NG - 1), bi = blockIdx.x >> 3;
  const int lo = g * RANGE;
  const int hi = min(n, lo + RANGE);
  const int* base = part + (size_t)(g * BPG + bi) * RANGE;
  for (int ii = threadIdx.x; ii < RANGE; ii += 256) cur[ii] = base[ii];
  __syncthreads();
  const int quads = E >> 2;
  const int per = (quads + BPG - 1) / BPG;
  const int q0 = bi * per, q1 = min(quads, q0 + per);
  const int4* s4 = (const int4*)ei;
  const int4* d4 = (const int4*)(ei + E);
  for (int q = q0 + threadIdx.x; q < q1; q += 256) {
    int4 s = s4[q], d = d4[q];
    if (d.x >= lo && d.x < hi) csr[atomicAdd(&cur[d.x - lo], 1)] = s.x;
    if (d.y >= lo && d.y < hi) csr[atomicAdd(&cur[d.y - lo], 1)] = s.y;
    if (d.z >= lo && d.z < hi) csr[atomicAdd(&cur[d.z - lo], 1)] = s.z;
    if (d.w >= lo && d.w < hi) csr[atomicAdd(&cur[d.w - lo], 1)] = s.w;
  }
  if (bi == 0) {
    for (int e = (quads << 2) + threadIdx.x; e < E; e += 256) {
      int d = ei[E + e];
      if (d >= lo && d < hi) csr[atomicAdd(&cur[d - lo], 1)] = ei[e];
    }
  }
}

// ---------------- weight pack: fp32 [K,N] -> f16 fragment layout ----------
struct PW { const float* src; unsigned short* dst; int K, Ncols, colOff, NnTot; };
struct PWArr { PW d[7]; };

__global__ void k_packw(PWArr a) {
  PW d = a.d[blockIdx.y];
  int t = blockIdx.x * blockDim.x + threadIdx.x;
  if (t >= d.K * d.Ncols) return;
  int k = t / d.Ncols;
  int n = t - k * d.Ncols;
  float v = d.src[t];
  d.dst[((size_t)(k >> 3) * d.NnTot + d.colOff + n) * 8 + (k & 7)] =
      __builtin_bit_cast(unsigned short, (_Float16)v);
}

// ---------------- fp8 owner-lane aggregation (round-7 form) ---------------
// Per node: stage up to 64 csr indices in a private LDS row (1 coalesced
// read), then gather with broadcast-index loads — 8 gathers in flight,
// no dependent global loads in the loop. Grid-stride persistent waves.
// OUTK 0: Yv = f16 stream [n][W]   OUTK 1: Yv = fp8 table, tanh epilogue
template <int W, int OUTK>
__global__ __launch_bounds__(256) void k_agg8(
    const unsigned char* __restrict__ X8, void* __restrict__ Yv,
    const int* __restrict__ degI, const float* __restrict__ dis,
    const int* __restrict__ ptr, const int* __restrict__ csr,
    const float* __restrict__ bias, int n) {
  constexpr int LPR = W / 2;    // lanes per row
  constexpr int NB = 64 / LPR;  // edge slots per issue
  __shared__ int idxs[4][72];   // per-wave private index stage (64 + pad)
  const int wvw = threadIdx.x >> 6;
  const int l = threadIdx.x & 63;
  const int sub = l / LPR;
  const int boff = (l % LPR) * 2;
  const unsigned char* __restrict__ Xb = X8 + boff;
  const int stride = gridDim.x * 4;

  for (int i = blockIdx.x * 4 + wvw; i < n; i += stride) {
    const int p0 = ptr[i];
    const int cnt = degI[i];
    if (l < cnt) idxs[wvw][l] = csr[p0 + l];
    floatx2 acc;
    {
      uint u = *(const unsigned short*)(Xb + (size_t)i * W);
      floatx2 f = up8(u);
      acc.x = (sub == 0) ? f.x : 0.f;
      acc.y = (sub == 0) ? f.y : 0.f;
    }
    const int m = min(cnt, 64);
    int e = 0;
    if (NB == 1) {
      for (; e + 8 <= m; e += 8) {
        int4 q0 = *(const int4*)&idxs[wvw][e];
        int4 q1 = *(const int4*)&idxs[wvw][e + 4];
        uint u0 = *(const unsigned short*)(Xb + ((uint)q0.x << 7));
        uint u1 = *(const unsigned short*)(Xb + ((uint)q0.y << 7));
        uint u2 = *(const unsigned short*)(Xb + ((uint)q0.z << 7));
        uint u3 = *(const unsigned short*)(Xb + ((uint)q0.w << 7));
        uint u4 = *(const unsigned short*)(Xb + ((uint)q1.x << 7));
        uint u5 = *(const unsigned short*)(Xb + ((uint)q1.y << 7));
        uint u6 = *(const unsigned short*)(Xb + ((uint)q1.z << 7));
        uint u7 = *(const unsigned short*)(Xb + ((uint)q1.w << 7));
        acc += up8(u0) + up8(u1);
        acc += up8(u2) + up8(u3);
        acc += up8(u4) + up8(u5);
        acc += up8(u6) + up8(u7);
      }
      for (; e < m; ++e) {
        int s = idxs[wvw][e];
        acc += up8(*(const unsigned short*)(Xb + ((uint)s << 7)));
      }
      for (; e < cnt; ++e) {  // rare: degree > 64
        int s = csr[p0 + e];
        acc += up8(*(const unsigned short*)(Xb + ((uint)s << 7)));
      }
    } else {
      constexpr int SH = (W == 64) ? 6 : 5;
      for (; e + 4 * NB <= m; e += 4 * NB) {
        int s0 = idxs[wvw][e + sub];
        int s1 = idxs[wvw][e + NB + sub];
        int s2 = idxs[wvw][e + 2 * NB + sub];
        int s3 = idxs[wvw][e + 3 * NB + sub];
        uint u0 = *(const unsigned short*)(Xb + ((uint)s0 << SH));
        uint u1 = *(const unsigned short*)(Xb + ((uint)s1 << SH));
        uint u2 = *(const unsigned short*)(Xb + ((uint)s2 << SH));
        uint u3 = *(const unsigned short*)(Xb + ((uint)s3 << SH));
        acc += up8(u0) + up8(u1);
        acc += up8(u2) + up8(u3);
      }
      for (; e < m; e += NB) {
        int ii = e + sub;
        if (ii < m)
          acc += up8(*(const unsigned short*)(Xb + ((uint)idxs[wvw][ii] << SH)));
      }
      for (; e < cnt; e += NB) {  // rare: degree > 64
        int ii = e + sub;
        if (ii < cnt)
          acc += up8(*(const unsigned short*)(Xb + ((uint)csr[p0 + ii] << SH)));
      }
#pragma unroll
      for (int mask = LPR; mask < 64; mask <<= 1) {
        acc.x += __shfl_xor(acc.x, mask);
        acc.y += __shfl_xor(acc.y, mask);
      }
    }
    if (sub == 0) {
      float di = dis[i];
      float a0 = di * acc.x, a1 = di * acc.y;
      if (OUTK == 1) {
        float2 b = *(const float2*)&bias[boff];
        uint p = pk8(di * tanhf(a0 + b.x), di * tanhf(a1 + b.y));
        *(unsigned short*)((unsigned char*)Yv + (size_t)i * W + boff) =
            (unsigned short)p;
      } else {
        *(uint*)((unsigned char*)Yv + ((size_t)i * W + boff) * 2) = pk2(a0, a1);
      }
    }
  }
}

// ---------------- MFMA f16 GEMM, NN=128, BM=128 (4 waves x 32 rows) -------
// MODE 0: O8 = fp8(dis*tanh(v+b1))   MODE 1: mean/lv/z fused   MODE 2: O1 = v+b1
template <int KT, int MODE>
__global__ __launch_bounds__(256) void k_gemm16(
    const _Float16* __restrict__ A1, int K1,
    const _Float16* __restrict__ A2, int K2,
    const unsigned short* __restrict__ Wp,
    const float* __restrict__ b1, const float* __restrict__ b2,
    float* __restrict__ O1, float* __restrict__ O2, float* __restrict__ O3,
    unsigned char* __restrict__ O8,
    const float* __restrict__ noise, const float* __restrict__ dis, int M) {
  __shared__ unsigned short wl[(KT / 8) * 1024];
  const int tid = threadIdx.x;
  const int l = tid & 63, wid = tid >> 6;
  const int row0 = blockIdx.x * 128;
  constexpr int totalU16 = (KT / 8) * 1024;
  for (int o = tid * 8; o < totalU16; o += 256 * 8) {
    *(uint4*)&wl[o] = *(const uint4*)&Wp[o];
  }
  __syncthreads();

  const int ar = l & 15, kg = l >> 4;
  f32x4 acc[2][8] = {};
  for (int k0 = 0; k0 < KT; k0 += 32) {
    const _Float16* Ab;
    int kl, Kb;
    if (k0 < K1) { Ab = A1; kl = k0; Kb = K1; }
    else         { Ab = A2; kl = k0 - K1; Kb = K2; }
    f16x8 a[2];
#pragma unroll
    for (int mt = 0; mt < 2; mt++) {
      int row = row0 + wid * 32 + mt * 16 + ar;
      if (row < M) {
        a[mt] = *(const f16x8*)&Ab[(size_t)row * Kb + kl + kg * 8];
      } else {
#pragma unroll
        for (int j = 0; j < 8; j++) a[mt][j] = (_Float16)0;
      }
    }
    int lb = ((k0 >> 3) + kg) * 1024 + ar * 8;
#pragma unroll
    for (int nt = 0; nt < 8; nt++) {
      f16x8 b = *(const f16x8*)&wl[lb + nt * 128];
#pragma unroll
      for (int mt = 0; mt < 2; mt++)
        acc[mt][nt] = __builtin_amdgcn_mfma_f32_16x16x32_f16(a[mt], b, acc[mt][nt], 0, 0, 0);
    }
  }

#pragma unroll
  for (int mt = 0; mt < 2; mt++) {
    int rbase = row0 + wid * 32 + mt * 16 + (l >> 4) * 4;
#pragma unroll
    for (int r = 0; r < 4; r++) {
      int rw = rbase + r;
      if (rw >= M) continue;
      if (MODE == 1) {
#pragma unroll
        for (int nt = 0; nt < 4; nt++) {
          int c = nt * 16 + (l & 15);
          float mv = acc[mt][nt][r] + b1[c];
          float lv = acc[mt][nt + 4][r] + b2[c];
          O1[(size_t)rw * 64 + c] = mv;
          O2[(size_t)rw * 64 + c] = lv;
          float z = noise[(size_t)rw * 64 + c] * expf(0.5f * lv) + mv;
          O3[(size_t)rw * 64 + c] = z;
        }
      } else if (MODE == 0) {
        float dr = dis[rw];
#pragma unroll
        for (int nt = 0; nt < 8; nt++) {
          int c = nt * 16 + (l & 15);
          float v = tanhf(acc[mt][nt][r] + b1[c]);
          O8[(size_t)rw * 128 + c] = pk8b(dr * v);
        }
      } else {
#pragma unroll
        for (int nt = 0; nt < 8; nt++) {
          int c = nt * 16 + (l & 15);
          O1[(size_t)rw * 128 + c] = acc[mt][nt][r] + b1[c];
        }
      }
    }
  }
}

// ---------------- P1 GEMM: fp32 [A|B] inputs (KA+KB=KT), prescaled fp8 out
// Used for encoder layer 1 ([feat|cond], K=160) and decoder layer 1
// ([z|cond], K=96). Output = fp8( dis[row] * (X @ W) )  (bias/tanh applied
// later in the agg epilogue).
template <int KT, int KA>
__global__ __launch_bounds__(256) void k_gemmP1(
    const float* __restrict__ A, const float* __restrict__ B,
    const unsigned short* __restrict__ Wp, unsigned char* __restrict__ O8,
    const float* __restrict__ dis, int M) {
  constexpr int KB = KT - KA;
  __shared__ unsigned short wl[(KT / 8) * 1024];
  const int tid = threadIdx.x;
  const int l = tid & 63, wid = tid >> 6;
  const int row0 = blockIdx.x * 128;
  constexpr int totalU16 = (KT / 8) * 1024;
  for (int o = tid * 8; o < totalU16; o += 256 * 8) {
    *(uint4*)&wl[o] = *(const uint4*)&Wp[o];
  }
  __syncthreads();

  const int ar = l & 15, kg = l >> 4;
  f32x4 acc[2][8] = {};
  for (int k0 = 0; k0 < KT; k0 += 32) {
    int col0 = k0 + kg * 8;
    f16x8 a[2];
#pragma unroll
    for (int mt = 0; mt < 2; mt++) {
      int row = row0 + wid * 32 + mt * 16 + ar;
      float4 u = {0, 0, 0, 0}, v = {0, 0, 0, 0};
      if (row < M) {
        if (col0 < KA) {
          u = *(const float4*)&A[(size_t)row * KA + col0];
          v = *(const float4*)&A[(size_t)row * KA + col0 + 4];
        } else {
          u = *(const float4*)&B[(size_t)row * KB + (col0 - KA)];
          v = *(const float4*)&B[(size_t)row * KB + (col0 - KA + 4)];
        }
      }
      a[mt][0] = (_Float16)u.x; a[mt][1] = (_Float16)u.y;
      a[mt][2] = (_Float16)u.z; a[mt][3] = (_Float16)u.w;
      a[mt][4] = (_Float16)v.x; a[mt][5] = (_Float16)v.y;
      a[mt][6] = (_Float16)v.z; a[mt][7] = (_Float16)v.w;
    }
    int lb = ((k0 >> 3) + kg) * 1024 + ar * 8;
#pragma unroll
    for (int nt = 0; nt < 8; nt++) {
      f16x8 b = *(const f16x8*)&wl[lb + nt * 128];
#pragma unroll
      for (int mt = 0; mt < 2; mt++)
        acc[mt][nt] = __builtin_amdgcn_mfma_f32_16x16x32_f16(a[mt], b, acc[mt][nt], 0, 0, 0);
    }
  }
#pragma unroll
  for (int mt = 0; mt < 2; mt++) {
    int rbase = row0 + wid * 32 + mt * 16 + (l >> 4) * 4;
#pragma unroll
    for (int r = 0; r < 4; r++) {
      int rw = rbase + r;
      if (rw >= M) continue;
      float dr = dis[rw];
#pragma unroll
      for (int nt = 0; nt < 8; nt++) {
        int c = nt * 16 + (l & 15);
        O8[(size_t)rw * 128 + c] = pk8b(dr * acc[mt][nt][r]);
      }
    }
  }
}

// ---------------------------------------------------------------------------

static inline size_t align_up(size_t x, size_t a) { return (x + a - 1) & ~(a - 1); }

extern "C" void kernel_launch(void* const* d_in, const int* in_sizes, int n_in,
                              void* d_out, int out_size, void* d_ws, size_t ws_size,
                              hipStream_t stream) {
  const float* feature   = (const float*)d_in[0];
  const float* condition = (const float*)d_in[1];
  const float* noise     = (const float*)d_in[2];
  const int*   ei        = (const int*)d_in[3];
  const float* Wenc1 = (const float*)d_in[4];  const float* benc1 = (const float*)d_in[5];
  const float* Wenc2 = (const float*)d_in[6];  const float* benc2 = (const float*)d_in[7];
  const float* Wm    = (const float*)d_in[8];  const float* bm    = (const float*)d_in[9];
  const float* Wlv   = (const float*)d_in[10]; const float* blv   = (const float*)d_in[11];
  const float* Wd1   = (const float*)d_in[12]; const float* bd1   = (const float*)d_in[13];
  const float* Wd2   = (const float*)d_in[14]; const float* bd2   = (const float*)d_in[15];
  const float* Wout  = (const float*)d_in[16]; const float* bout  = (const float*)d_in[17];

  const int N = in_sizes[0] / FEAT;
  const int E = in_sizes[3] / 2;

  // ---- d_out segments ----
  float* out = (float*)d_out;
  float* zseg    = out;
  float* meanseg = out + (size_t)N * LAT;
  float* lvseg   = out + (size_t)2 * N * LAT;
  float* outseg  = out + (size_t)3 * N * LAT;  // fp32 [N,128]; untouched until final GEMM

  // ---- workspace ----
  char* w = (char*)d_ws;
  size_t off = 0;
  int*   degI   = (int*)(w + off);   off = align_up(off + (size_t)N * 4, 256);
  float* dis    = (float*)(w + off); off = align_up(off + (size_t)N * 4, 256);
  int*   ptr    = (int*)(w + off);   off = align_up(off + (size_t)N * 4, 256);
  int*   blkSum = (int*)(w + off);   off = align_up(off + 4096, 256);
  int*   blkOff = (int*)(w + off);   off = align_up(off + 4096, 256);
  int*   csr    = (int*)(w + off);   off = align_up(off + (size_t)(E + 64) * 4, 256);
  unsigned short* WpE1 = (unsigned short*)(w + off); off = align_up(off + 160 * 128 * 2, 256);
  unsigned short* WpE2 = (unsigned short*)(w + off); off = align_up(off + 128 * 128 * 2, 256);
  unsigned short* WpML = (unsigned short*)(w + off); off = align_up(off + 128 * 128 * 2, 256);
  unsigned short* WpD1 = (unsigned short*)(w + off); off = align_up(off + 96 * 128 * 2, 256);
  unsigned short* WpD2 = (unsigned short*)(w + off); off = align_up(off + 128 * 128 * 2, 256);
  unsigned short* WpO  = (unsigned short*)(w + off); off = align_up(off + 128 * 128 * 2, 256);
  _Float16* TA = (_Float16*)(w + off); off = align_up(off + (size_t)N * 128 * 2, 256);
  unsigned char* F8A = (unsigned char*)(w + off); off = align_up(off + (size_t)N * 128, 256);
  unsigned char* F8B = (unsigned char*)(w + off); off = align_up(off + (size_t)N * 128, 256);
  // partial-count slab aliases TA (dead until first f16 stream write)
  int* part = (int*)TA;  // [NG*BPG][RANGE] = 12.8 MB < 25.6 MB

  const int TB_ = 256;
  dim3 blk(TB_);
  dim3 gN((N + TB_ - 1) / TB_);
  const int nScanBlk = (N + 1023) / 1024;
  dim3 gAgg(2048);   // persistent grid-stride waves: 32 waves/CU
  dim3 gG((N + 127) / 128);
  dim3 gPart(NG * BPG);

  // ---- graph prep (no global atomics) ----
  k_hist<<<gPart, blk, 0, stream>>>(ei + E, part, E, N);
  k_scan1<<<dim3(nScanBlk), blk, 0, stream>>>(part, degI, dis, ptr, blkSum, N);
  k_scan2<<<dim3(1), blk, 0, stream>>>(blkSum, blkOff, nScanBlk);
  k_scan3<<<gN, blk, 0, stream>>>(ptr, blkOff, N);
  k_cum<<<gN, blk, 0, stream>>>(part, ptr, N);
  k_fill2<<<gPart, blk, 0, stream>>>(ei, part, csr, E, N);

  // ---- weight packing ----
  {
    PWArr pa;
    pa.d[0] = {Wenc1, WpE1, 160, 128, 0, 128};
    pa.d[1] = {Wenc2, WpE2, 128, 128, 0, 128};
    pa.d[2] = {Wm,    WpML, 128, 64,  0, 128};
    pa.d[3] = {Wlv,   WpML, 128, 64, 64, 128};
    pa.d[4] = {Wd1,   WpD1,  96, 128, 0, 128};
    pa.d[5] = {Wd2,   WpD2, 128, 128, 0, 128};
    pa.d[6] = {Wout,  WpO,  128, 128, 0, 128};
    k_packw<<<dim3(80, 7), blk, 0, stream>>>(pa);
  }

  // ---- encoder ----
  // P1 = [feat|cond]@Wenc1, prescaled fp8 -> F8A
  k_gemmP1<160, 128><<<gG, blk, 0, stream>>>(feature, condition, WpE1, F8A, dis, N);
  // h1' = fp8( dis*tanh(agg(P1)+b1) ) -> F8B
  k_agg8<HID, 1><<<gAgg, blk, 0, stream>>>(F8A, F8B, degI, dis, ptr, csr, benc1, N);
  // agg(h1') -> TA (f16 stream)
  k_agg8<HID, 0><<<gAgg, blk, 0, stream>>>(F8B, TA, degI, dis, ptr, csr, nullptr, N);
  // h2' = fp8( dis*tanh(TA@We2+b2) ) -> F8A
  k_gemm16<128, 0><<<gG, blk, 0, stream>>>(
      TA, HID, nullptr, 0, WpE2, benc2, nullptr,
      nullptr, nullptr, nullptr, F8A, nullptr, dis, N);
  // agg(h2') -> TA
  k_agg8<HID, 0><<<gAgg, blk, 0, stream>>>(F8A, TA, degI, dis, ptr, csr, nullptr, N);
  // mean/lv/z (fp32 outputs to d_out)
  k_gemm16<128, 1><<<gG, blk, 0, stream>>>(
      TA, HID, nullptr, 0, WpML, bm, blv,
      meanseg, lvseg, zseg, nullptr, noise, dis, N);

  // ---- decoder (mult-first layer 1, mirroring encoder) ----
  // P1d = [z|cond]@Wd1, prescaled fp8 -> F8A
  k_gemmP1<96, 64><<<gG, blk, 0, stream>>>(zseg, condition, WpD1, F8A, dis, N);
  // g1' = fp8( dis*tanh(agg(P1d)+bd1) ) -> F8B
  k_agg8<HID, 1><<<gAgg, blk, 0, stream>>>(F8A, F8B, degI, dis, ptr, csr, bd1, N);
  // agg(g1') -> TA
  k_agg8<HID, 0><<<gAgg, blk, 0, stream>>>(F8B, TA, degI, dis, ptr, csr, nullptr, N);
  // g2' = fp8( dis*tanh(TA@Wd2+b) ) -> F8A
  k_gemm16<128, 0><<<gG, blk, 0, stream>>>(
      TA, HID, nullptr, 0, WpD2, bd2, nullptr,
      nullptr, nullptr, nullptr, F8A, nullptr, dis, N);
  // agg(g2') -> TA
  k_agg8<HID, 0><<<gAgg, blk, 0, stream>>>(F8A, TA, degI, dis, ptr, csr, nullptr, N);
  // out = TA@Wout + b -> outseg (fp32)
  k_gemm16<128, 2><<<gG, blk, 0, stream>>>(
      TA, HID, nullptr, 0, WpO, bout, nullptr,
      outseg, nullptr, nullptr, nullptr, nullptr, dis, N);
}